// Round 8
// baseline (744.340 us; speedup 1.0000x reference)
//
#include <hip/hip_runtime.h>
#include <hip/hip_bf16.h>
#include <math.h>

#define N_NODES 50000
#define N_EDGES 800000
#define NP 50048  // N rounded up to 64

typedef __hip_bfloat16 bf16;
typedef __attribute__((ext_vector_type(8))) short short8;
typedef __attribute__((ext_vector_type(4))) float f32x4;

__device__ __forceinline__ float lrelu(float x) { return x > 0.f ? x : 0.2f * x; }

__device__ __forceinline__ short f2b(float v) {
    bf16 h = __float2bfloat16(v);
    return *reinterpret_cast<short*>(&h);
}
__device__ __forceinline__ float lo_bf(unsigned u) { return __uint_as_float(u << 16); }
__device__ __forceinline__ float hi_bf(unsigned u) { return __uint_as_float(u & 0xFFFF0000u); }
__device__ __forceinline__ float b2f_s(unsigned short s) {
    return __uint_as_float(((unsigned)s) << 16);
}
__device__ __forceinline__ unsigned pack_bf(float v0, float v1) {
    unsigned a = (unsigned)(unsigned short)f2b(v0);
    unsigned b = (unsigned)(unsigned short)f2b(v1);
    return a | (b << 16);
}
__device__ __forceinline__ float sigm(float x) { return 1.f / (1.f + expf(-x)); }

// ---------------------------------------------------------------------------
// Fast x_all slice packer (unchanged from round 6).
// ---------------------------------------------------------------------------
template <int CPR, int K, int OFF>
__global__ __launch_bounds__(256) void pack_x_kernel(
    const float* __restrict__ x, short* __restrict__ out, int nrows)
{
    int chunk = blockIdx.x * 256 + threadIdx.x;
    int r = chunk / CPR;
    int c8 = (chunk - r * CPR) * 8;
    if (r >= NP) return;
    short8 tmp;
    if (r < nrows) {
        const float* p = x + (size_t)r * 441 + OFF + c8;
#pragma unroll
        for (int j = 0; j < 8; j++) {
            int k = c8 + j;
            tmp[j] = (k < K) ? f2b(p[j]) : (short)0;
        }
    } else {
#pragma unroll
        for (int j = 0; j < 8; j++) tmp[j] = 0;
    }
    *(short8*)(out + (size_t)r * (CPR * 8) + c8) = tmp;
}

// ---------------------------------------------------------------------------
// Batched f32 -> bf16 packer for the (small) weight tensors.
// ---------------------------------------------------------------------------
struct PackDesc {
    const float* src;
    short* dst;
    int lda, M, K, Mp, Kp;
};
struct PackArgs {
    PackDesc d[16];
    unsigned long long sz[16];
    int n;
};

__global__ __launch_bounds__(256) void pack_all_kernel(PackArgs pa,
                                                       unsigned long long total)
{
    for (unsigned long long i =
             (unsigned long long)blockIdx.x * blockDim.x + threadIdx.x;
         i < total; i += (unsigned long long)gridDim.x * blockDim.x) {
        unsigned long long off = i;
        int s = 0;
        while (s < pa.n - 1 && off >= pa.sz[s]) { off -= pa.sz[s]; s++; }
        PackDesc D = pa.d[s];
        int r = (int)(off / (unsigned)D.Kp);
        int k = (int)(off % (unsigned)D.Kp);
        float v = (r < D.M && k < D.K) ? D.src[(size_t)r * D.lda + k] : 0.f;
        D.dst[(size_t)r * D.Kp + k] = f2b(v);
    }
}

// ---------------------------------------------------------------------------
// Per-wave branch step used inside mega1: phase1 (K1 -> M1, sigmoid, via LDS),
// phase2 (M1 -> M2, relu, back into LDS), then accumulate conv1 partial
// products for this branch's column range. All per-wave, no barriers.
// ---------------------------------------------------------------------------
template <int CT1, int CT2, int KI1, int ADT>
__device__ __forceinline__ void branch_step(
    const void* __restrict__ Av, int lda, int aoff, int K1, int arow, int nrows,
    const short* __restrict__ W1p, const float* __restrict__ B1,
    const short* __restrict__ W2p, const float* __restrict__ B2,
    short (* __restrict__ sHw)[136],
    const short* __restrict__ conv1p, int coff,
    int lrow, int quad, f32x4* __restrict__ cacc)
{
    constexpr int M1 = CT1 * 16;
    constexpr int M2 = CT2 * 16;
    constexpr int LDW1 = KI1 * 32;

    // ---- phase 1: h = sigm(W1 @ a + b1) ----
    {
        f32x4 acc[CT1];
#pragma unroll
        for (int ct = 0; ct < CT1; ct++)
#pragma unroll
            for (int i = 0; i < 4; i++) acc[ct][i] = 0.f;

#pragma unroll
        for (int ki = 0; ki < KI1; ki++) {
            short8 a;
            if (ADT == 1) {
                a = *(const short8*)((const short*)Av + (size_t)arow * lda +
                                     ki * 32 + quad * 8);
            } else {
                const float* Af = (const float*)Av;
                bool rok = arow < nrows;
#pragma unroll
                for (int j = 0; j < 8; j++) {
                    int k = ki * 32 + quad * 8 + j;
                    a[j] = (rok && k < K1)
                               ? f2b(Af[(size_t)arow * lda + aoff + k])
                               : (short)0;
                }
            }
#pragma unroll
            for (int ct = 0; ct < CT1; ct++) {
                short8 b = *(const short8*)(W1p + (size_t)(ct * 16 + lrow) * LDW1 +
                                            ki * 32 + quad * 8);
                acc[ct] = __builtin_amdgcn_mfma_f32_16x16x32_bf16(a, b, acc[ct], 0, 0, 0);
            }
        }
#pragma unroll
        for (int ct = 0; ct < CT1; ct++) {
            int col = ct * 16 + lrow;
            float bv = B1[col];
#pragma unroll
            for (int i = 0; i < 4; i++)
                sHw[quad * 4 + i][col] = f2b(sigm(acc[ct][i] + bv));
        }
    }

    // ---- phase 2: out = relu(W2 @ h + b2), overwritten into sHw ----
    {
        f32x4 acc[CT2];
#pragma unroll
        for (int ct = 0; ct < CT2; ct++)
#pragma unroll
            for (int i = 0; i < 4; i++) acc[ct][i] = 0.f;

#pragma unroll
        for (int ki = 0; ki < M1 / 32; ki++) {
            short8 a = *(short8*)&sHw[lrow][ki * 32 + quad * 8];
#pragma unroll
            for (int ct = 0; ct < CT2; ct++) {
                short8 b = *(const short8*)(W2p + (size_t)(ct * 16 + lrow) * M1 +
                                            ki * 32 + quad * 8);
                acc[ct] = __builtin_amdgcn_mfma_f32_16x16x32_bf16(a, b, acc[ct], 0, 0, 0);
            }
        }
#pragma unroll
        for (int ct = 0; ct < CT2; ct++) {
            int col = ct * 16 + lrow;
            float bv = B2[col];
#pragma unroll
            for (int i = 0; i < 4; i++)
                sHw[quad * 4 + i][col] = f2b(fmaxf(acc[ct][i] + bv, 0.f));
        }
    }

    // ---- conv1 partial: k-range [coff, coff+M2) ----
#pragma unroll
    for (int ki = 0; ki < M2 / 32; ki++) {
        short8 a = *(short8*)&sHw[lrow][ki * 32 + quad * 8];
#pragma unroll
        for (int ct = 0; ct < 8; ct++) {
            short8 b = *(const short8*)(conv1p + (size_t)(ct * 16 + lrow) * 384 +
                                        coff + ki * 32 + quad * 8);
            cacc[ct] = __builtin_amdgcn_mfma_f32_16x16x32_bf16(a, b, cacc[ct], 0, 0, 0);
        }
    }
}

// ---------------------------------------------------------------------------
// mega1: four fused MLP branches + conv1 GEMM + attention scores, one pass.
// The N x 384 concat is never materialized. Writes hw (Bb) + ssrc/sdst.
// ---------------------------------------------------------------------------
template <int PACKX>
__global__ __launch_bounds__(256) void mega1_kernel(
    const float* __restrict__ x_all,
    const short* __restrict__ xs3, const short* __restrict__ xs4,
    const short* __restrict__ s1p, const float* __restrict__ s1b,
    const short* __restrict__ s5p, const float* __restrict__ s5b,
    const short* __restrict__ s2p, const float* __restrict__ s2b,
    const short* __restrict__ s6p, const float* __restrict__ s6b,
    const short* __restrict__ s3p, const float* __restrict__ s3b,
    const short* __restrict__ s7p, const float* __restrict__ s7b,
    const short* __restrict__ s4p, const float* __restrict__ s4b,
    const short* __restrict__ s8p, const float* __restrict__ s8b,
    const short* __restrict__ conv1p,
    const float* __restrict__ a_src, const float* __restrict__ a_dst,
    short* __restrict__ Bb, float* __restrict__ ssrc, float* __restrict__ sdst,
    int nrows)
{
    __shared__ short sH[4][16][136];

    int tid = threadIdx.x;
    int row0 = blockIdx.x * 64;
    int wv = tid >> 6, lane = tid & 63;
    int lrow = lane & 15, quad = lane >> 4;
    int arow = row0 + wv * 16 + lrow;
    short (*sHw)[136] = sH[wv];

    f32x4 cacc[8];
#pragma unroll
    for (int ct = 0; ct < 8; ct++)
#pragma unroll
        for (int i = 0; i < 4; i++) cacc[ct][i] = 0.f;

    // branch 1: x_all[:,1:3] -> 64 -> 64, concat cols [0,64)
    branch_step<4, 4, 1, 0>(x_all, 441, 1, 2, arow, nrows,
                            s1p, s1b, s5p, s5b, sHw, conv1p, 0, lrow, quad, cacc);
    // branch 2: x_all[:,3:16] -> 64 -> 64, cols [64,128)
    branch_step<4, 4, 1, 0>(x_all, 441, 3, 13, arow, nrows,
                            s2p, s2b, s6p, s6b, sHw, conv1p, 64, lrow, quad, cacc);
    // branch 3: x_all[:,16:56] -> 128 -> 128, cols [128,256)
    if (PACKX)
        branch_step<8, 8, 2, 1>(xs3, 64, 0, 64, arow, nrows,
                                s3p, s3b, s7p, s7b, sHw, conv1p, 128, lrow, quad, cacc);
    else
        branch_step<8, 8, 2, 0>(x_all, 441, 16, 40, arow, nrows,
                                s3p, s3b, s7p, s7b, sHw, conv1p, 128, lrow, quad, cacc);
    // branch 4: x_all[:,56:421] -> 128 -> 128, cols [256,384)
    if (PACKX)
        branch_step<8, 8, 12, 1>(xs4, 384, 0, 384, arow, nrows,
                                 s4p, s4b, s8p, s8b, sHw, conv1p, 256, lrow, quad, cacc);
    else
        branch_step<8, 8, 12, 0>(x_all, 441, 56, 365, arow, nrows,
                                 s4p, s4b, s8p, s8b, sHw, conv1p, 256, lrow, quad, cacc);

    // ---- epilogue: write hw (no activation) + attention scores ----
#pragma unroll
    for (int ct = 0; ct < 8; ct++) {
        int gcol = ct * 16 + lrow;
#pragma unroll
        for (int i = 0; i < 4; i++) {
            int grow = row0 + wv * 16 + quad * 4 + i;
            Bb[(size_t)grow * 128 + gcol] = f2b(cacc[ct][i]);
        }
    }
    float as_c[8], ad_c[8];
#pragma unroll
    for (int ct = 0; ct < 8; ct++) {
        int gcol = ct * 16 + lrow;
        as_c[ct] = a_src[gcol];
        ad_c[ct] = a_dst[gcol];
    }
#pragma unroll
    for (int i = 0; i < 4; i++) {
        float ps = 0.f, pd = 0.f;
#pragma unroll
        for (int ct = 0; ct < 8; ct++) {
            ps = fmaf(cacc[ct][i], as_c[ct], ps);
            pd = fmaf(cacc[ct][i], ad_c[ct], pd);
        }
#pragma unroll
        for (int off = 8; off > 0; off >>= 1) {
            ps += __shfl_down(ps, off);
            pd += __shfl_down(pd, off);
        }
        if (lrow == 0) {
            int grow = row0 + wv * 16 + quad * 4 + i;
            if (grow < nrows) { ssrc[grow] = ps; sdst[grow] = pd; }
        }
    }
}

// ---------------------------------------------------------------------------
// Direct-from-global MFMA GEMM (conv2 / conv3).
// ---------------------------------------------------------------------------
template <int ACT, int ODT, int CT, int KI, int SCORES>
__global__ __launch_bounds__(256) void dgemm_kernel(
    const short* __restrict__ A, int lda,
    const short* __restrict__ W,
    const float* __restrict__ bias,
    void* __restrict__ Cv, int ldc, int coff, int nrows, int M,
    const float* __restrict__ a_src, const float* __restrict__ a_dst,
    float* __restrict__ ssrc, float* __restrict__ sdst)
{
    constexpr int LDW = KI * 32;
    int tid = threadIdx.x;
    int row0 = blockIdx.x * 64;
    int wv = tid >> 6, lane = tid & 63;
    int lrow = lane & 15, quad = lane >> 4;

    const short* Ap = A + (size_t)(row0 + wv * 16 + lrow) * lda + quad * 8;
    const short* Wp = W + (size_t)lrow * LDW + quad * 8;

    f32x4 acc[CT];
#pragma unroll
    for (int ct = 0; ct < CT; ct++)
#pragma unroll
        for (int i = 0; i < 4; i++) acc[ct][i] = 0.f;

#pragma unroll 4
    for (int ki = 0; ki < KI; ki++) {
        short8 a = *(const short8*)(Ap + ki * 32);
#pragma unroll
        for (int ct = 0; ct < CT; ct++) {
            short8 b = *(const short8*)(Wp + (size_t)ct * 16 * LDW + ki * 32);
            acc[ct] = __builtin_amdgcn_mfma_f32_16x16x32_bf16(a, b, acc[ct], 0, 0, 0);
        }
    }

    float* Cf = (float*)Cv;
    bf16*  Cb = (bf16*)Cv;
#pragma unroll
    for (int ct = 0; ct < CT; ct++) {
        int gcol = ct * 16 + lrow;
        if (gcol >= M) continue;
        float bv = bias ? bias[gcol] : 0.f;
#pragma unroll
        for (int i = 0; i < 4; i++) {
            int grow = row0 + wv * 16 + quad * 4 + i;
            if (grow >= nrows) continue;
            float v = acc[ct][i] + bv;
            if (ACT == 1) v = fmaxf(v, 0.f);
            if (ACT == 2) v = sigm(v);
            if (ODT == 1) Cb[(size_t)grow * ldc + coff + gcol] = __float2bfloat16(v);
            else          Cf[(size_t)grow * ldc + coff + gcol] = v;
        }
    }

    if (SCORES) {
        float as_c[CT], ad_c[CT];
#pragma unroll
        for (int ct = 0; ct < CT; ct++) {
            int gcol = ct * 16 + lrow;
            as_c[ct] = (gcol < M) ? a_src[gcol] : 0.f;
            ad_c[ct] = (gcol < M) ? a_dst[gcol] : 0.f;
        }
#pragma unroll
        for (int i = 0; i < 4; i++) {
            float ps = 0.f, pd = 0.f;
#pragma unroll
            for (int ct = 0; ct < CT; ct++) {
                ps = fmaf(acc[ct][i], as_c[ct], ps);
                pd = fmaf(acc[ct][i], ad_c[ct], pd);
            }
#pragma unroll
            for (int off = 8; off > 0; off >>= 1) {
                ps += __shfl_down(ps, off);
                pd += __shfl_down(pd, off);
            }
            if (lrow == 0) {
                int grow = row0 + wv * 16 + quad * 4 + i;
                if (grow < nrows) { ssrc[grow] = ps; sdst[grow] = pd; }
            }
        }
    }
}

// ---------------------------------------------------------------------------
// Fused head: concat(gat3_out, lstm_h) -> lin1(relu) -> lin2(relu) -> lin3.
// ---------------------------------------------------------------------------
__global__ __launch_bounds__(256) void head_kernel(
    const bf16* __restrict__ xg, const float* __restrict__ x_all,
    const float* __restrict__ wih, const float* __restrict__ bih,
    const float* __restrict__ bhh,
    const short* __restrict__ w1p, const float* __restrict__ b1,
    const short* __restrict__ w2p, const float* __restrict__ b2,
    const short* __restrict__ w3p, const float* __restrict__ b3,
    float* __restrict__ dout, int n)
{
    __shared__ short sW[20][200];
    __shared__ float sT[64][20];
    __shared__ short sX[64][136];
    __shared__ short sH2[64][72];
    __shared__ short sH3[64][72];

    int tid = threadIdx.x;
    int row0 = blockIdx.x * 64;
    int wv = tid >> 6, lane = tid & 63;
    int lrow = lane & 15, quad = lane >> 4;

    for (int i = tid; i < 20 * 192; i += 256) {
        int k = i / 192, j = i % 192;
        int gate = j >> 6, jj = j & 63;
        int srow = (gate == 0) ? jj : (gate == 1 ? 128 + jj : 192 + jj);
        sW[k][j] = f2b(wih[srow * 20 + k]);
    }
    for (int i = tid; i < 64 * 20; i += 256) {
        int r = i / 20, k = i % 20;
        int grow = row0 + r;
        sT[r][k] = (grow < n) ? x_all[(size_t)grow * 441 + 421 + k] : 0.f;
    }
    for (int i = tid; i < 64 * 8; i += 256) {
        int r = i >> 3, c8 = (i & 7) * 8;
        int grow = row0 + r;
        short8 tmp;
        if (grow < n) {
            tmp = *(const short8*)(((const short*)xg) + (size_t)grow * 64 + c8);
        } else {
#pragma unroll
            for (int j = 0; j < 8; j++) tmp[j] = 0;
        }
        *(short8*)&sX[r][c8] = tmp;
    }
    __syncthreads();

    for (int p = 0; p < 16; p++) {
        int idx = p * 256 + tid;
        int r = idx >> 6, j = idx & 63;
        float gi = 0.f, gg = 0.f, go = 0.f;
#pragma unroll
        for (int k = 0; k < 20; k++) {
            float t = sT[r][k];
            gi = fmaf(t, b2f_s((unsigned short)sW[k][j]), gi);
            gg = fmaf(t, b2f_s((unsigned short)sW[k][64 + j]), gg);
            go = fmaf(t, b2f_s((unsigned short)sW[k][128 + j]), go);
        }
        gi += bih[j] + bhh[j];
        gg += bih[128 + j] + bhh[128 + j];
        go += bih[192 + j] + bhh[192 + j];
        float c = sigm(gi) * tanhf(gg);
        float h = sigm(go) * tanhf(c);
        sX[r][64 + j] = f2b(h);
    }
    __syncthreads();

    f32x4 acc[4];
#pragma unroll
    for (int ct = 0; ct < 4; ct++)
#pragma unroll
        for (int i = 0; i < 4; i++) acc[ct][i] = 0.f;
#pragma unroll
    for (int ki = 0; ki < 4; ki++) {
        short8 a = *(short8*)&sX[wv * 16 + lrow][ki * 32 + quad * 8];
#pragma unroll
        for (int ct = 0; ct < 4; ct++) {
            short8 b = *(const short8*)(w1p + (size_t)(ct * 16 + lrow) * 128 +
                                        ki * 32 + quad * 8);
            acc[ct] = __builtin_amdgcn_mfma_f32_16x16x32_bf16(a, b, acc[ct], 0, 0, 0);
        }
    }
#pragma unroll
    for (int ct = 0; ct < 4; ct++) {
        int col = ct * 16 + lrow;
        float bv = b1[col];
#pragma unroll
        for (int i = 0; i < 4; i++)
            sH2[wv * 16 + quad * 4 + i][col] = f2b(fmaxf(acc[ct][i] + bv, 0.f));
    }

#pragma unroll
    for (int ct = 0; ct < 4; ct++)
#pragma unroll
        for (int i = 0; i < 4; i++) acc[ct][i] = 0.f;
#pragma unroll
    for (int ki = 0; ki < 2; ki++) {
        short8 a = *(short8*)&sH2[wv * 16 + lrow][ki * 32 + quad * 8];
#pragma unroll
        for (int ct = 0; ct < 4; ct++) {
            short8 b = *(const short8*)(w2p + (size_t)(ct * 16 + lrow) * 64 +
                                        ki * 32 + quad * 8);
            acc[ct] = __builtin_amdgcn_mfma_f32_16x16x32_bf16(a, b, acc[ct], 0, 0, 0);
        }
    }
#pragma unroll
    for (int ct = 0; ct < 4; ct++) {
        int col = ct * 16 + lrow;
        float bv = b2[col];
#pragma unroll
        for (int i = 0; i < 4; i++)
            sH3[wv * 16 + quad * 4 + i][col] = f2b(fmaxf(acc[ct][i] + bv, 0.f));
    }

#pragma unroll
    for (int ct = 0; ct < 4; ct++)
#pragma unroll
        for (int i = 0; i < 4; i++) acc[ct][i] = 0.f;
#pragma unroll
    for (int ki = 0; ki < 2; ki++) {
        short8 a = *(short8*)&sH3[wv * 16 + lrow][ki * 32 + quad * 8];
#pragma unroll
        for (int ct = 0; ct < 4; ct++) {
            short8 b = *(const short8*)(w3p + (size_t)(ct * 16 + lrow) * 64 +
                                        ki * 32 + quad * 8);
            acc[ct] = __builtin_amdgcn_mfma_f32_16x16x32_bf16(a, b, acc[ct], 0, 0, 0);
        }
    }
#pragma unroll
    for (int ct = 0; ct < 4; ct++) {
        int gcol = ct * 16 + lrow;
        if (gcol >= 56) continue;
        float bv = b3[gcol];
#pragma unroll
        for (int i = 0; i < 4; i++) {
            int grow = row0 + wv * 16 + quad * 4 + i;
            if (grow >= n) continue;
            dout[(size_t)grow * 56 + gcol] = acc[ct][i] + bv;
        }
    }
}

// ---------------------------------------------------------------------------
// Fused GAT aggregation (single CSR pass; max-shift cancels in softmax).
// ---------------------------------------------------------------------------
template <int FPL>
__global__ __launch_bounds__(256) void gat_fused_kernel(
    const bf16* __restrict__ hw, const int* __restrict__ rowptr,
    const int* __restrict__ colidx, const float* __restrict__ ss,
    const float* __restrict__ sd, const float* __restrict__ bias,
    bf16* __restrict__ out, int ldc, int coff, int n, int F)
{
    int wv = threadIdx.x >> 6, lane = threadIdx.x & 63;
    int node = blockIdx.x * 4 + wv;
    if (node >= n) return;
    const unsigned short* hwu = (const unsigned short*)hw;
    float sdn = sd[node];
    float wself = expf(lrelu(ss[node] + sdn));
    float a0, a1 = 0.f;
    if (FPL == 2) {
        unsigned u = *(const unsigned*)(hwu + (size_t)node * F + 2 * lane);
        a0 = wself * lo_bf(u);
        a1 = wself * hi_bf(u);
    } else {
        a0 = wself * b2f_s(hwu[(size_t)node * F + lane]);
    }
    int e0 = rowptr[node];
    int deg = rowptr[node + 1] - e0;
    float den_l = 0.f;
    for (int c0 = 0; c0 < deg; c0 += 64) {
        int mye = c0 + lane;
        int s = 0;
        float w = 0.f;
        if (mye < deg) {
            s = colidx[e0 + mye];
            w = expf(lrelu(ss[s] + sdn));
        }
        den_l += w;
        int cnt = min(64, deg - c0);
        int j = 0;
        for (; j + 1 < cnt; j += 2) {
            int s0 = __shfl(s, j), s1 = __shfl(s, j + 1);
            float w0 = __shfl(w, j), w1v = __shfl(w, j + 1);
            if (FPL == 2) {
                unsigned u0 = *(const unsigned*)(hwu + (size_t)s0 * F + 2 * lane);
                unsigned u1 = *(const unsigned*)(hwu + (size_t)s1 * F + 2 * lane);
                a0 = fmaf(w0, lo_bf(u0), a0);
                a1 = fmaf(w0, hi_bf(u0), a1);
                a0 = fmaf(w1v, lo_bf(u1), a0);
                a1 = fmaf(w1v, hi_bf(u1), a1);
            } else {
                float h0 = b2f_s(hwu[(size_t)s0 * F + lane]);
                float h1 = b2f_s(hwu[(size_t)s1 * F + lane]);
                a0 = fmaf(w0, h0, a0);
                a0 = fmaf(w1v, h1, a0);
            }
        }
        if (j < cnt) {
            int s0 = __shfl(s, j);
            float w0 = __shfl(w, j);
            if (FPL == 2) {
                unsigned u0 = *(const unsigned*)(hwu + (size_t)s0 * F + 2 * lane);
                a0 = fmaf(w0, lo_bf(u0), a0);
                a1 = fmaf(w0, hi_bf(u0), a1);
            } else {
                a0 = fmaf(w0, b2f_s(hwu[(size_t)s0 * F + lane]), a0);
            }
        }
    }
#pragma unroll
    for (int off = 32; off > 0; off >>= 1) den_l += __shfl_xor(den_l, off);
    float inv = 1.f / (den_l + wself);
    if (FPL == 2) {
        float v0 = fmaxf(a0 * inv + bias[2 * lane], 0.f);
        float v1 = fmaxf(a1 * inv + bias[2 * lane + 1], 0.f);
        unsigned* op = (unsigned*)(out + (size_t)node * ldc + coff);
        op[lane] = pack_bf(v0, v1);
    } else {
        out[(size_t)node * ldc + coff + lane] =
            __float2bfloat16(fmaxf(a0 * inv + bias[lane], 0.f));
    }
}

// ---------------------------------------------------------------------------
// CSR build: count (atomic) -> 3-phase parallel scan -> fill (atomic).
// ---------------------------------------------------------------------------
__global__ void count_kernel(const int* __restrict__ dst, int* __restrict__ cnt,
                             int e)
{
    for (int i = blockIdx.x * blockDim.x + threadIdx.x; i < e;
         i += gridDim.x * blockDim.x)
        atomicAdd(cnt + dst[i], 1);
}

#define SCAN_BLOCKS 256

__global__ __launch_bounds__(256) void scan_local_kernel(
    const int* __restrict__ cnt, int* __restrict__ rowptr,
    int* __restrict__ bsum, int n, int chunk)
{
    __shared__ int tmp[256];
    int b = blockIdx.x, tid = threadIdx.x;
    int i = b * chunk + tid;
    int v = (tid < chunk && i < n) ? cnt[i] : 0;
    tmp[tid] = v;
    __syncthreads();
    for (int off = 1; off < 256; off <<= 1) {
        int t = (tid >= off) ? tmp[tid - off] : 0;
        __syncthreads();
        tmp[tid] += t;
        __syncthreads();
    }
    if (tid < chunk && i < n) rowptr[i] = tmp[tid] - v;
    if (tid == 255) bsum[b] = tmp[255];
}

__global__ __launch_bounds__(256) void scan_bsums_kernel(
    int* __restrict__ bsum, int* __restrict__ rowptr, int n)
{
    __shared__ int tmp[256];
    int tid = threadIdx.x;
    int v = bsum[tid];
    tmp[tid] = v;
    __syncthreads();
    for (int off = 1; off < 256; off <<= 1) {
        int t = (tid >= off) ? tmp[tid - off] : 0;
        __syncthreads();
        tmp[tid] += t;
        __syncthreads();
    }
    bsum[tid] = tmp[tid] - v;
    if (tid == 255) rowptr[n] = tmp[255];
}

__global__ __launch_bounds__(256) void scan_add_kernel(
    int* __restrict__ rowptr, int* __restrict__ nextp,
    const int* __restrict__ bsum, int n, int chunk)
{
    int b = blockIdx.x, tid = threadIdx.x;
    int i = b * chunk + tid;
    if (tid < chunk && i < n) {
        int v = rowptr[i] + bsum[b];
        rowptr[i] = v;
        nextp[i] = v;
    }
}

__global__ void fill_kernel(const int* __restrict__ src,
                            const int* __restrict__ dst,
                            int* __restrict__ nextp, int* __restrict__ colidx,
                            int e)
{
    for (int i = blockIdx.x * blockDim.x + threadIdx.x; i < e;
         i += gridDim.x * blockDim.x) {
        int pos = atomicAdd(nextp + dst[i], 1);
        colidx[pos] = src[i];
    }
}

// ---------------------------------------------------------------------------
extern "C" void kernel_launch(void* const* d_in, const int* in_sizes, int n_in,
                              void* d_out, int out_size, void* d_ws,
                              size_t ws_size, hipStream_t stream)
{
    const int N = N_NODES;
    const int E = N_EDGES;

    const float* x_all = (const float*)d_in[0];
    const int* edges = (const int*)d_in[1];
    const int* e_src = edges;
    const int* e_dst = edges + E;

    const float* sep1_w = (const float*)d_in[2];  const float* sep1_b = (const float*)d_in[3];
    const float* sep2_w = (const float*)d_in[4];  const float* sep2_b = (const float*)d_in[5];
    const float* sep3_w = (const float*)d_in[6];  const float* sep3_b = (const float*)d_in[7];
    const float* sep4_w = (const float*)d_in[8];  const float* sep4_b = (const float*)d_in[9];
    const float* sep5_w = (const float*)d_in[10]; const float* sep5_b = (const float*)d_in[11];
    const float* sep6_w = (const float*)d_in[12]; const float* sep6_b = (const float*)d_in[13];
    const float* sep7_w = (const float*)d_in[14]; const float* sep7_b = (const float*)d_in[15];
    const float* sep8_w = (const float*)d_in[16]; const float* sep8_b = (const float*)d_in[17];
    const float* conv1_w = (const float*)d_in[18];
    const float* conv1_as = (const float*)d_in[19];
    const float* conv1_ad = (const float*)d_in[20];
    const float* conv1_b = (const float*)d_in[21];
    const float* conv2_w = (const float*)d_in[22];
    const float* conv2_as = (const float*)d_in[23];
    const float* conv2_ad = (const float*)d_in[24];
    const float* conv2_b = (const float*)d_in[25];
    const float* conv3_w = (const float*)d_in[26];
    const float* conv3_as = (const float*)d_in[27];
    const float* conv3_ad = (const float*)d_in[28];
    const float* conv3_b = (const float*)d_in[29];
    const float* lstm_wih = (const float*)d_in[30];
    const float* lstm_bih = (const float*)d_in[32];
    const float* lstm_bhh = (const float*)d_in[33];
    const float* lin1_w = (const float*)d_in[34]; const float* lin1_b = (const float*)d_in[35];
    const float* lin2_w = (const float*)d_in[36]; const float* lin2_b = (const float*)d_in[37];
    const float* lin3_w = (const float*)d_in[38]; const float* lin3_b = (const float*)d_in[39];

    char* ws = (char*)d_ws;
    size_t off = 0;
    auto alloc = [&](size_t bytes) {
        void* p = ws + off;
        off += (bytes + 255) & ~(size_t)255;
        return p;
    };
    short* x0 = (short*)alloc((size_t)NP * 384 * 2);  // reused for C / xg
    short* Bb = (short*)alloc((size_t)NP * 128 * 2);  // hw buffer
    float* ssrc = (float*)alloc((size_t)N * 4);
    float* sdst = (float*)alloc((size_t)N * 4);
    int* rowptr = (int*)alloc((size_t)(N + 1) * 4);
    int* nextp  = (int*)alloc((size_t)N * 4);
    int* cnt    = (int*)alloc((size_t)N * 4);
    int* bsum   = (int*)alloc((size_t)SCAN_BLOCKS * 4);
    int* colidx = (int*)alloc((size_t)E * 4);

    short* conv1p = (short*)alloc((size_t)128 * 384 * 2);
    short* conv2p = (short*)alloc((size_t)128 * 128 * 2);
    short* conv3p = (short*)alloc((size_t)64 * 128 * 2);
    short* sep1p  = (short*)alloc((size_t)64 * 32 * 2);
    short* sep2p  = (short*)alloc((size_t)64 * 32 * 2);
    short* sep3p  = (short*)alloc((size_t)128 * 64 * 2);
    short* sep4p  = (short*)alloc((size_t)128 * 384 * 2);
    short* sep5p  = (short*)alloc((size_t)64 * 64 * 2);
    short* sep6p  = (short*)alloc((size_t)64 * 64 * 2);
    short* sep7p  = (short*)alloc((size_t)128 * 128 * 2);
    short* sep8p  = (short*)alloc((size_t)128 * 128 * 2);
    short* lin1p  = (short*)alloc((size_t)64 * 128 * 2);
    short* lin2p  = (short*)alloc((size_t)64 * 64 * 2);
    short* lin3p  = (short*)alloc((size_t)64 * 64 * 2);

    size_t need_xs = off + (size_t)NP * 64 * 2 + (size_t)NP * 384 * 2 + 1024;
    bool packx = ws_size >= need_xs;
    short* xs3 = packx ? (short*)alloc((size_t)NP * 64 * 2) : nullptr;
    short* xs4 = packx ? (short*)alloc((size_t)NP * 384 * 2) : nullptr;

    short* C  = x0;       // GAT ping buffer (N,128)
    bf16* xg = (bf16*)x0; // GAT3 out (N,64)

    dim3 blk(256);
    int gx = NP / 64;  // 782
    int nb4 = (N + 3) / 4;
    int chunk = (N + SCAN_BLOCKS - 1) / SCAN_BLOCKS;

    // --- CSR build ---
    hipMemsetAsync(cnt, 0, (size_t)N * 4, stream);
    count_kernel<<<1024, 256, 0, stream>>>(e_dst, cnt, E);
    scan_local_kernel<<<SCAN_BLOCKS, 256, 0, stream>>>(cnt, rowptr, bsum, N, chunk);
    scan_bsums_kernel<<<1, 256, 0, stream>>>(bsum, rowptr, N);
    scan_add_kernel<<<SCAN_BLOCKS, 256, 0, stream>>>(rowptr, nextp, bsum, N, chunk);
    fill_kernel<<<1024, 256, 0, stream>>>(e_src, e_dst, nextp, colidx, E);

    // --- pack x slices (fast path) + weights (generic) to bf16 ---
    if (packx) {
        pack_x_kernel<48, 365, 56><<<(NP * 48 + 255) / 256, blk, 0, stream>>>(
            x_all, xs4, N);
        pack_x_kernel<8, 40, 16><<<(NP * 8 + 255) / 256, blk, 0, stream>>>(
            x_all, xs3, N);
    }
    {
        PackArgs pa{};
        unsigned long long total = 0;
        int np = 0;
        auto addp = [&](const float* src, short* dst, int lda, int M, int K,
                        int Mp, int Kp) {
            pa.d[np].src = src; pa.d[np].dst = dst; pa.d[np].lda = lda;
            pa.d[np].M = M; pa.d[np].K = K; pa.d[np].Mp = Mp; pa.d[np].Kp = Kp;
            pa.sz[np] = (unsigned long long)Mp * Kp;
            total += pa.sz[np];
            np++;
        };
        addp(conv1_w, conv1p, 384, 128, 384, 128, 384);
        addp(sep4_w, sep4p, 365, 128, 365, 128, 384);
        addp(conv2_w, conv2p, 128, 128, 128, 128, 128);
        addp(sep7_w, sep7p, 128, 128, 128, 128, 128);
        addp(sep8_w, sep8p, 128, 128, 128, 128, 128);
        addp(conv3_w, conv3p, 128, 64, 128, 64, 128);
        addp(lin1_w, lin1p, 128, 64, 128, 64, 128);
        addp(sep3_w, sep3p, 40, 128, 40, 128, 64);
        addp(sep5_w, sep5p, 64, 64, 64, 64, 64);
        addp(sep6_w, sep6p, 64, 64, 64, 64, 64);
        addp(lin2_w, lin2p, 64, 64, 64, 64, 64);
        addp(lin3_w, lin3p, 64, 56, 64, 64, 64);
        addp(sep1_w, sep1p, 2, 64, 2, 64, 32);
        addp(sep2_w, sep2p, 13, 64, 13, 64, 32);
        pa.n = np;
        pack_all_kernel<<<512, 256, 0, stream>>>(pa, total);
    }

    // --- mega1: 4 branches + conv1 + scores in one pass ---
    if (packx) {
        mega1_kernel<1><<<gx, blk, 0, stream>>>(
            x_all, xs3, xs4,
            sep1p, sep1_b, sep5p, sep5_b, sep2p, sep2_b, sep6p, sep6_b,
            sep3p, sep3_b, sep7p, sep7_b, sep4p, sep4_b, sep8p, sep8_b,
            conv1p, conv1_as, conv1_ad, Bb, ssrc, sdst, N);
    } else {
        mega1_kernel<0><<<gx, blk, 0, stream>>>(
            x_all, xs3, xs4,
            sep1p, sep1_b, sep5p, sep5_b, sep2p, sep2_b, sep6p, sep6_b,
            sep3p, sep3_b, sep7p, sep7_b, sep4p, sep4_b, sep8p, sep8_b,
            conv1p, conv1_as, conv1_ad, Bb, ssrc, sdst, N);
    }
    gat_fused_kernel<2><<<nb4, 256, 0, stream>>>(
        (const bf16*)Bb, rowptr, colidx, ssrc, sdst, conv1_b, (bf16*)C, 128, 0, N, 128);

    dgemm_kernel<0, 1, 8, 4, 1><<<gx, blk, 0, stream>>>(
        C, 128, conv2p, nullptr, Bb, 128, 0, N, 128,
        conv2_as, conv2_ad, ssrc, sdst);
    gat_fused_kernel<2><<<nb4, 256, 0, stream>>>(
        (const bf16*)Bb, rowptr, colidx, ssrc, sdst, conv2_b, (bf16*)C, 128, 0, N, 128);

    dgemm_kernel<0, 1, 4, 4, 1><<<gx, blk, 0, stream>>>(
        C, 128, conv3p, nullptr, Bb, 64, 0, N, 64,
        conv3_as, conv3_ad, ssrc, sdst);
    gat_fused_kernel<1><<<nb4, 256, 0, stream>>>(
        (const bf16*)Bb, rowptr, colidx, ssrc, sdst, conv3_b, xg, 64, 0, N, 64);

    // --- fused head: lstm + lin1 + lin2 + lin3 ---
    head_kernel<<<gx, blk, 0, stream>>>(
        xg, x_all, lstm_wih, lstm_bih, lstm_bhh,
        lin1p, lin1_b, lin2p, lin2_b, lin3p, lin3_b,
        (float*)d_out, N);
}

// Round 9
// 705.749 us; speedup vs baseline: 1.0547x; 1.0547x over previous
//
#include <hip/hip_runtime.h>
#include <hip/hip_bf16.h>
#include <math.h>

#define N_NODES 50000
#define N_EDGES 800000
#define NP 50048  // N rounded up to 64

typedef __hip_bfloat16 bf16;
typedef __attribute__((ext_vector_type(8))) short short8;
typedef __attribute__((ext_vector_type(4))) float f32x4;

__device__ __forceinline__ float lrelu(float x) { return x > 0.f ? x : 0.2f * x; }

__device__ __forceinline__ short f2b(float v) {
    bf16 h = __float2bfloat16(v);
    return *reinterpret_cast<short*>(&h);
}
__device__ __forceinline__ float lo_bf(unsigned u) { return __uint_as_float(u << 16); }
__device__ __forceinline__ float hi_bf(unsigned u) { return __uint_as_float(u & 0xFFFF0000u); }
__device__ __forceinline__ float b2f_s(unsigned short s) {
    return __uint_as_float(((unsigned)s) << 16);
}
__device__ __forceinline__ unsigned pack_bf(float v0, float v1) {
    unsigned a = (unsigned)(unsigned short)f2b(v0);
    unsigned b = (unsigned)(unsigned short)f2b(v1);
    return a | (b << 16);
}
__device__ __forceinline__ float sigm(float x) { return 1.f / (1.f + expf(-x)); }

// ---------------------------------------------------------------------------
// Fast x_all slice packer.
// ---------------------------------------------------------------------------
template <int CPR, int K, int OFF>
__global__ __launch_bounds__(256) void pack_x_kernel(
    const float* __restrict__ x, short* __restrict__ out, int nrows)
{
    int chunk = blockIdx.x * 256 + threadIdx.x;
    int r = chunk / CPR;
    int c8 = (chunk - r * CPR) * 8;
    if (r >= NP) return;
    short8 tmp;
    if (r < nrows) {
        const float* p = x + (size_t)r * 441 + OFF + c8;
#pragma unroll
        for (int j = 0; j < 8; j++) {
            int k = c8 + j;
            tmp[j] = (k < K) ? f2b(p[j]) : (short)0;
        }
    } else {
#pragma unroll
        for (int j = 0; j < 8; j++) tmp[j] = 0;
    }
    *(short8*)(out + (size_t)r * (CPR * 8) + c8) = tmp;
}

// ---------------------------------------------------------------------------
// Batched f32 -> bf16 packer for the (small) weight tensors.
// ---------------------------------------------------------------------------
struct PackDesc {
    const float* src;
    short* dst;
    int lda, M, K, Mp, Kp;
};
struct PackArgs {
    PackDesc d[16];
    unsigned long long sz[16];
    int n;
};

__global__ __launch_bounds__(256) void pack_all_kernel(PackArgs pa,
                                                       unsigned long long total)
{
    for (unsigned long long i =
             (unsigned long long)blockIdx.x * blockDim.x + threadIdx.x;
         i < total; i += (unsigned long long)gridDim.x * blockDim.x) {
        unsigned long long off = i;
        int s = 0;
        while (s < pa.n - 1 && off >= pa.sz[s]) { off -= pa.sz[s]; s++; }
        PackDesc D = pa.d[s];
        int r = (int)(off / (unsigned)D.Kp);
        int k = (int)(off % (unsigned)D.Kp);
        float v = (r < D.M && k < D.K) ? D.src[(size_t)r * D.lda + k] : 0.f;
        D.dst[(size_t)r * D.Kp + k] = f2b(v);
    }
}

// ---------------------------------------------------------------------------
// Direct-from-global MFMA GEMM with full A-fragment register prefetch.
// ---------------------------------------------------------------------------
template <int ACT, int ODT, int CT, int KI, int SCORES>
__global__ __launch_bounds__(256) void dgemm_kernel(
    const short* __restrict__ A, int lda,
    const short* __restrict__ W,
    const float* __restrict__ bias,
    void* __restrict__ Cv, int ldc, int coff, int nrows, int M,
    const float* __restrict__ a_src, const float* __restrict__ a_dst,
    float* __restrict__ ssrc, float* __restrict__ sdst)
{
    constexpr int LDW = KI * 32;
    int tid = threadIdx.x;
    int row0 = blockIdx.x * 64;
    int wv = tid >> 6, lane = tid & 63;
    int lrow = lane & 15, quad = lane >> 4;

    const short* Ap = A + (size_t)(row0 + wv * 16 + lrow) * lda + quad * 8;
    const short* Wp = W + (size_t)lrow * LDW + quad * 8;

    // prefetch all A fragments (all loads issued before first use)
    short8 areg[KI];
#pragma unroll
    for (int ki = 0; ki < KI; ki++) areg[ki] = *(const short8*)(Ap + ki * 32);

    f32x4 acc[CT];
#pragma unroll
    for (int ct = 0; ct < CT; ct++)
#pragma unroll
        for (int i = 0; i < 4; i++) acc[ct][i] = 0.f;

#pragma unroll
    for (int ki = 0; ki < KI; ki++) {
#pragma unroll
        for (int ct = 0; ct < CT; ct++) {
            short8 b = *(const short8*)(Wp + (size_t)ct * 16 * LDW + ki * 32);
            acc[ct] = __builtin_amdgcn_mfma_f32_16x16x32_bf16(areg[ki], b, acc[ct], 0, 0, 0);
        }
    }

    float* Cf = (float*)Cv;
    bf16*  Cb = (bf16*)Cv;
#pragma unroll
    for (int ct = 0; ct < CT; ct++) {
        int gcol = ct * 16 + lrow;
        if (gcol >= M) continue;
        float bv = bias ? bias[gcol] : 0.f;
#pragma unroll
        for (int i = 0; i < 4; i++) {
            int grow = row0 + wv * 16 + quad * 4 + i;
            if (grow >= nrows) continue;
            float v = acc[ct][i] + bv;
            if (ACT == 1) v = fmaxf(v, 0.f);
            if (ACT == 2) v = sigm(v);
            if (ODT == 1) Cb[(size_t)grow * ldc + coff + gcol] = __float2bfloat16(v);
            else          Cf[(size_t)grow * ldc + coff + gcol] = v;
        }
    }

    if (SCORES) {
        float as_c[CT], ad_c[CT];
#pragma unroll
        for (int ct = 0; ct < CT; ct++) {
            int gcol = ct * 16 + lrow;
            as_c[ct] = (gcol < M) ? a_src[gcol] : 0.f;
            ad_c[ct] = (gcol < M) ? a_dst[gcol] : 0.f;
        }
#pragma unroll
        for (int i = 0; i < 4; i++) {
            float ps = 0.f, pd = 0.f;
#pragma unroll
            for (int ct = 0; ct < CT; ct++) {
                ps = fmaf(acc[ct][i], as_c[ct], ps);
                pd = fmaf(acc[ct][i], ad_c[ct], pd);
            }
#pragma unroll
            for (int off = 8; off > 0; off >>= 1) {
                ps += __shfl_down(ps, off);
                pd += __shfl_down(pd, off);
            }
            if (lrow == 0) {
                int grow = row0 + wv * 16 + quad * 4 + i;
                if (grow < nrows) { ssrc[grow] = ps; sdst[grow] = pd; }
            }
        }
    }
}

// ---------------------------------------------------------------------------
// Fused 2-layer MLP branch with A prefetch: out = relu(W2@sig(W1@a+b1)+b2).
// ---------------------------------------------------------------------------
template <int ADT, int CT1, int CT2, int KI1>
__global__ __launch_bounds__(256) void brmlp_kernel(
    const void* __restrict__ Av, int lda, int aoff,
    const short* __restrict__ W1p, const float* __restrict__ B1,
    const short* __restrict__ W2p, const float* __restrict__ B2,
    bf16* __restrict__ out, int ldc, int coff, int nrows, int K1)
{
    constexpr int M1 = CT1 * 16;
    constexpr int LDH = M1 + 8;
    constexpr int LDW1 = KI1 * 32;
    __shared__ short sH[64][LDH];

    int tid = threadIdx.x;
    int row0 = blockIdx.x * 64;
    int wv = tid >> 6, lane = tid & 63;
    int lrow = lane & 15, quad = lane >> 4;
    int arow = row0 + wv * 16 + lrow;

    // ---- phase 1 ----
    {
        short8 areg[KI1];
        if (ADT == 1) {
#pragma unroll
            for (int ki = 0; ki < KI1; ki++)
                areg[ki] = *(const short8*)((const short*)Av + (size_t)arow * lda +
                                            ki * 32 + quad * 8);
        } else {
            const float* Af = (const float*)Av;
            bool rok = arow < nrows;
#pragma unroll
            for (int ki = 0; ki < KI1; ki++)
#pragma unroll
                for (int j = 0; j < 8; j++) {
                    int k = ki * 32 + quad * 8 + j;
                    areg[ki][j] = (rok && k < K1)
                                      ? f2b(Af[(size_t)arow * lda + aoff + k])
                                      : (short)0;
                }
        }

        f32x4 acc[CT1];
#pragma unroll
        for (int ct = 0; ct < CT1; ct++)
#pragma unroll
            for (int i = 0; i < 4; i++) acc[ct][i] = 0.f;

#pragma unroll
        for (int ki = 0; ki < KI1; ki++) {
#pragma unroll
            for (int ct = 0; ct < CT1; ct++) {
                short8 b = *(const short8*)(W1p + (size_t)(ct * 16 + lrow) * LDW1 +
                                            ki * 32 + quad * 8);
                acc[ct] = __builtin_amdgcn_mfma_f32_16x16x32_bf16(areg[ki], b, acc[ct], 0, 0, 0);
            }
        }
#pragma unroll
        for (int ct = 0; ct < CT1; ct++) {
            int col = ct * 16 + lrow;
            float bv = B1[col];
#pragma unroll
            for (int i = 0; i < 4; i++)
                sH[wv * 16 + quad * 4 + i][col] = f2b(sigm(acc[ct][i] + bv));
        }
    }

    // ---- phase 2 (K2 = M1); per-wave rows, no barrier needed ----
    {
        f32x4 acc[CT2];
#pragma unroll
        for (int ct = 0; ct < CT2; ct++)
#pragma unroll
            for (int i = 0; i < 4; i++) acc[ct][i] = 0.f;

#pragma unroll
        for (int ki = 0; ki < M1 / 32; ki++) {
            short8 a = *(short8*)&sH[wv * 16 + lrow][ki * 32 + quad * 8];
#pragma unroll
            for (int ct = 0; ct < CT2; ct++) {
                short8 b = *(const short8*)(W2p + (size_t)(ct * 16 + lrow) * M1 +
                                            ki * 32 + quad * 8);
                acc[ct] = __builtin_amdgcn_mfma_f32_16x16x32_bf16(a, b, acc[ct], 0, 0, 0);
            }
        }
#pragma unroll
        for (int ct = 0; ct < CT2; ct++) {
            int gcol = ct * 16 + lrow;
            float bv = B2[gcol];
#pragma unroll
            for (int i = 0; i < 4; i++) {
                int grow = row0 + wv * 16 + quad * 4 + i;
                if (grow >= nrows) continue;
                float v = fmaxf(acc[ct][i] + bv, 0.f);
                out[(size_t)grow * ldc + coff + gcol] = __float2bfloat16(v);
            }
        }
    }
}

// ---------------------------------------------------------------------------
// Fused head: concat(gat3_out, lstm_h) -> lin1(relu) -> lin2(relu) -> lin3.
// ---------------------------------------------------------------------------
__global__ __launch_bounds__(256) void head_kernel(
    const bf16* __restrict__ xg, const float* __restrict__ x_all,
    const float* __restrict__ wih, const float* __restrict__ bih,
    const float* __restrict__ bhh,
    const short* __restrict__ w1p, const float* __restrict__ b1,
    const short* __restrict__ w2p, const float* __restrict__ b2,
    const short* __restrict__ w3p, const float* __restrict__ b3,
    float* __restrict__ dout, int n)
{
    __shared__ short sW[20][200];
    __shared__ float sT[64][20];
    __shared__ short sX[64][136];
    __shared__ short sH2[64][72];
    __shared__ short sH3[64][72];

    int tid = threadIdx.x;
    int row0 = blockIdx.x * 64;
    int wv = tid >> 6, lane = tid & 63;
    int lrow = lane & 15, quad = lane >> 4;

    for (int i = tid; i < 20 * 192; i += 256) {
        int k = i / 192, j = i % 192;
        int gate = j >> 6, jj = j & 63;
        int srow = (gate == 0) ? jj : (gate == 1 ? 128 + jj : 192 + jj);
        sW[k][j] = f2b(wih[srow * 20 + k]);
    }
    for (int i = tid; i < 64 * 20; i += 256) {
        int r = i / 20, k = i % 20;
        int grow = row0 + r;
        sT[r][k] = (grow < n) ? x_all[(size_t)grow * 441 + 421 + k] : 0.f;
    }
    for (int i = tid; i < 64 * 8; i += 256) {
        int r = i >> 3, c8 = (i & 7) * 8;
        int grow = row0 + r;
        short8 tmp;
        if (grow < n) {
            tmp = *(const short8*)(((const short*)xg) + (size_t)grow * 64 + c8);
        } else {
#pragma unroll
            for (int j = 0; j < 8; j++) tmp[j] = 0;
        }
        *(short8*)&sX[r][c8] = tmp;
    }
    __syncthreads();

    for (int p = 0; p < 16; p++) {
        int idx = p * 256 + tid;
        int r = idx >> 6, j = idx & 63;
        float gi = 0.f, gg = 0.f, go = 0.f;
#pragma unroll
        for (int k = 0; k < 20; k++) {
            float t = sT[r][k];
            gi = fmaf(t, b2f_s((unsigned short)sW[k][j]), gi);
            gg = fmaf(t, b2f_s((unsigned short)sW[k][64 + j]), gg);
            go = fmaf(t, b2f_s((unsigned short)sW[k][128 + j]), go);
        }
        gi += bih[j] + bhh[j];
        gg += bih[128 + j] + bhh[128 + j];
        go += bih[192 + j] + bhh[192 + j];
        float c = sigm(gi) * tanhf(gg);
        float h = sigm(go) * tanhf(c);
        sX[r][64 + j] = f2b(h);
    }
    __syncthreads();

    f32x4 acc[4];
#pragma unroll
    for (int ct = 0; ct < 4; ct++)
#pragma unroll
        for (int i = 0; i < 4; i++) acc[ct][i] = 0.f;
#pragma unroll
    for (int ki = 0; ki < 4; ki++) {
        short8 a = *(short8*)&sX[wv * 16 + lrow][ki * 32 + quad * 8];
#pragma unroll
        for (int ct = 0; ct < 4; ct++) {
            short8 b = *(const short8*)(w1p + (size_t)(ct * 16 + lrow) * 128 +
                                        ki * 32 + quad * 8);
            acc[ct] = __builtin_amdgcn_mfma_f32_16x16x32_bf16(a, b, acc[ct], 0, 0, 0);
        }
    }
#pragma unroll
    for (int ct = 0; ct < 4; ct++) {
        int col = ct * 16 + lrow;
        float bv = b1[col];
#pragma unroll
        for (int i = 0; i < 4; i++)
            sH2[wv * 16 + quad * 4 + i][col] = f2b(fmaxf(acc[ct][i] + bv, 0.f));
    }

#pragma unroll
    for (int ct = 0; ct < 4; ct++)
#pragma unroll
        for (int i = 0; i < 4; i++) acc[ct][i] = 0.f;
#pragma unroll
    for (int ki = 0; ki < 2; ki++) {
        short8 a = *(short8*)&sH2[wv * 16 + lrow][ki * 32 + quad * 8];
#pragma unroll
        for (int ct = 0; ct < 4; ct++) {
            short8 b = *(const short8*)(w2p + (size_t)(ct * 16 + lrow) * 64 +
                                        ki * 32 + quad * 8);
            acc[ct] = __builtin_amdgcn_mfma_f32_16x16x32_bf16(a, b, acc[ct], 0, 0, 0);
        }
    }
#pragma unroll
    for (int ct = 0; ct < 4; ct++) {
        int col = ct * 16 + lrow;
        float bv = b2[col];
#pragma unroll
        for (int i = 0; i < 4; i++)
            sH3[wv * 16 + quad * 4 + i][col] = f2b(fmaxf(acc[ct][i] + bv, 0.f));
    }

#pragma unroll
    for (int ct = 0; ct < 4; ct++)
#pragma unroll
        for (int i = 0; i < 4; i++) acc[ct][i] = 0.f;
#pragma unroll
    for (int ki = 0; ki < 2; ki++) {
        short8 a = *(short8*)&sH3[wv * 16 + lrow][ki * 32 + quad * 8];
#pragma unroll
        for (int ct = 0; ct < 4; ct++) {
            short8 b = *(const short8*)(w3p + (size_t)(ct * 16 + lrow) * 64 +
                                        ki * 32 + quad * 8);
            acc[ct] = __builtin_amdgcn_mfma_f32_16x16x32_bf16(a, b, acc[ct], 0, 0, 0);
        }
    }
#pragma unroll
    for (int ct = 0; ct < 4; ct++) {
        int gcol = ct * 16 + lrow;
        if (gcol >= 56) continue;
        float bv = b3[gcol];
#pragma unroll
        for (int i = 0; i < 4; i++) {
            int grow = row0 + wv * 16 + quad * 4 + i;
            if (grow >= n) continue;
            dout[(size_t)grow * 56 + gcol] = acc[ct][i] + bv;
        }
    }
}

// ---------------------------------------------------------------------------
// Fused GAT aggregation, inner loop unrolled x4 for MLP (4 row loads in flight).
// ---------------------------------------------------------------------------
template <int FPL>
__global__ __launch_bounds__(256) void gat_fused_kernel(
    const bf16* __restrict__ hw, const int* __restrict__ rowptr,
    const int* __restrict__ colidx, const float* __restrict__ ss,
    const float* __restrict__ sd, const float* __restrict__ bias,
    bf16* __restrict__ out, int ldc, int coff, int n, int F)
{
    int wv = threadIdx.x >> 6, lane = threadIdx.x & 63;
    int node = blockIdx.x * 4 + wv;
    if (node >= n) return;
    const unsigned short* hwu = (const unsigned short*)hw;
    float sdn = sd[node];
    float wself = expf(lrelu(ss[node] + sdn));
    float a0, a1 = 0.f;
    if (FPL == 2) {
        unsigned u = *(const unsigned*)(hwu + (size_t)node * F + 2 * lane);
        a0 = wself * lo_bf(u);
        a1 = wself * hi_bf(u);
    } else {
        a0 = wself * b2f_s(hwu[(size_t)node * F + lane]);
    }
    int e0 = rowptr[node];
    int deg = rowptr[node + 1] - e0;
    float den_l = 0.f;
    for (int c0 = 0; c0 < deg; c0 += 64) {
        int mye = c0 + lane;
        int s = 0;
        float w = 0.f;
        if (mye < deg) {
            s = colidx[e0 + mye];
            w = expf(lrelu(ss[s] + sdn));
        }
        den_l += w;
        int cnt = min(64, deg - c0);
        int j = 0;
        for (; j + 3 < cnt; j += 4) {
            int s0 = __shfl(s, j), s1 = __shfl(s, j + 1);
            int s2 = __shfl(s, j + 2), s3 = __shfl(s, j + 3);
            float w0 = __shfl(w, j), w1v = __shfl(w, j + 1);
            float w2v = __shfl(w, j + 2), w3v = __shfl(w, j + 3);
            if (FPL == 2) {
                unsigned u0 = *(const unsigned*)(hwu + (size_t)s0 * F + 2 * lane);
                unsigned u1 = *(const unsigned*)(hwu + (size_t)s1 * F + 2 * lane);
                unsigned u2 = *(const unsigned*)(hwu + (size_t)s2 * F + 2 * lane);
                unsigned u3 = *(const unsigned*)(hwu + (size_t)s3 * F + 2 * lane);
                a0 = fmaf(w0, lo_bf(u0), a0);  a1 = fmaf(w0, hi_bf(u0), a1);
                a0 = fmaf(w1v, lo_bf(u1), a0); a1 = fmaf(w1v, hi_bf(u1), a1);
                a0 = fmaf(w2v, lo_bf(u2), a0); a1 = fmaf(w2v, hi_bf(u2), a1);
                a0 = fmaf(w3v, lo_bf(u3), a0); a1 = fmaf(w3v, hi_bf(u3), a1);
            } else {
                float h0 = b2f_s(hwu[(size_t)s0 * F + lane]);
                float h1 = b2f_s(hwu[(size_t)s1 * F + lane]);
                float h2 = b2f_s(hwu[(size_t)s2 * F + lane]);
                float h3 = b2f_s(hwu[(size_t)s3 * F + lane]);
                a0 = fmaf(w0, h0, a0);
                a0 = fmaf(w1v, h1, a0);
                a0 = fmaf(w2v, h2, a0);
                a0 = fmaf(w3v, h3, a0);
            }
        }
        for (; j < cnt; j++) {
            int s0 = __shfl(s, j);
            float w0 = __shfl(w, j);
            if (FPL == 2) {
                unsigned u0 = *(const unsigned*)(hwu + (size_t)s0 * F + 2 * lane);
                a0 = fmaf(w0, lo_bf(u0), a0);
                a1 = fmaf(w0, hi_bf(u0), a1);
            } else {
                a0 = fmaf(w0, b2f_s(hwu[(size_t)s0 * F + lane]), a0);
            }
        }
    }
#pragma unroll
    for (int off = 32; off > 0; off >>= 1) den_l += __shfl_xor(den_l, off);
    float inv = 1.f / (den_l + wself);
    if (FPL == 2) {
        float v0 = fmaxf(a0 * inv + bias[2 * lane], 0.f);
        float v1 = fmaxf(a1 * inv + bias[2 * lane + 1], 0.f);
        unsigned* op = (unsigned*)(out + (size_t)node * ldc + coff);
        op[lane] = pack_bf(v0, v1);
    } else {
        out[(size_t)node * ldc + coff + lane] =
            __float2bfloat16(fmaxf(a0 * inv + bias[lane], 0.f));
    }
}

// ---------------------------------------------------------------------------
// CSR build: count (atomic) -> 3-phase parallel scan -> fill (atomic).
// ---------------------------------------------------------------------------
__global__ void count_kernel(const int* __restrict__ dst, int* __restrict__ cnt,
                             int e)
{
    for (int i = blockIdx.x * blockDim.x + threadIdx.x; i < e;
         i += gridDim.x * blockDim.x)
        atomicAdd(cnt + dst[i], 1);
}

#define SCAN_BLOCKS 256

__global__ __launch_bounds__(256) void scan_local_kernel(
    const int* __restrict__ cnt, int* __restrict__ rowptr,
    int* __restrict__ bsum, int n, int chunk)
{
    __shared__ int tmp[256];
    int b = blockIdx.x, tid = threadIdx.x;
    int i = b * chunk + tid;
    int v = (tid < chunk && i < n) ? cnt[i] : 0;
    tmp[tid] = v;
    __syncthreads();
    for (int off = 1; off < 256; off <<= 1) {
        int t = (tid >= off) ? tmp[tid - off] : 0;
        __syncthreads();
        tmp[tid] += t;
        __syncthreads();
    }
    if (tid < chunk && i < n) rowptr[i] = tmp[tid] - v;
    if (tid == 255) bsum[b] = tmp[255];
}

__global__ __launch_bounds__(256) void scan_bsums_kernel(
    int* __restrict__ bsum, int* __restrict__ rowptr, int n)
{
    __shared__ int tmp[256];
    int tid = threadIdx.x;
    int v = bsum[tid];
    tmp[tid] = v;
    __syncthreads();
    for (int off = 1; off < 256; off <<= 1) {
        int t = (tid >= off) ? tmp[tid - off] : 0;
        __syncthreads();
        tmp[tid] += t;
        __syncthreads();
    }
    bsum[tid] = tmp[tid] - v;
    if (tid == 255) rowptr[n] = tmp[255];
}

__global__ __launch_bounds__(256) void scan_add_kernel(
    int* __restrict__ rowptr, int* __restrict__ nextp,
    const int* __restrict__ bsum, int n, int chunk)
{
    int b = blockIdx.x, tid = threadIdx.x;
    int i = b * chunk + tid;
    if (tid < chunk && i < n) {
        int v = rowptr[i] + bsum[b];
        rowptr[i] = v;
        nextp[i] = v;
    }
}

__global__ void fill_kernel(const int* __restrict__ src,
                            const int* __restrict__ dst,
                            int* __restrict__ nextp, int* __restrict__ colidx,
                            int e)
{
    for (int i = blockIdx.x * blockDim.x + threadIdx.x; i < e;
         i += gridDim.x * blockDim.x) {
        int pos = atomicAdd(nextp + dst[i], 1);
        colidx[pos] = src[i];
    }
}

// ---------------------------------------------------------------------------
extern "C" void kernel_launch(void* const* d_in, const int* in_sizes, int n_in,
                              void* d_out, int out_size, void* d_ws,
                              size_t ws_size, hipStream_t stream)
{
    const int N = N_NODES;
    const int E = N_EDGES;

    const float* x_all = (const float*)d_in[0];
    const int* edges = (const int*)d_in[1];
    const int* e_src = edges;
    const int* e_dst = edges + E;

    const float* sep1_w = (const float*)d_in[2];  const float* sep1_b = (const float*)d_in[3];
    const float* sep2_w = (const float*)d_in[4];  const float* sep2_b = (const float*)d_in[5];
    const float* sep3_w = (const float*)d_in[6];  const float* sep3_b = (const float*)d_in[7];
    const float* sep4_w = (const float*)d_in[8];  const float* sep4_b = (const float*)d_in[9];
    const float* sep5_w = (const float*)d_in[10]; const float* sep5_b = (const float*)d_in[11];
    const float* sep6_w = (const float*)d_in[12]; const float* sep6_b = (const float*)d_in[13];
    const float* sep7_w = (const float*)d_in[14]; const float* sep7_b = (const float*)d_in[15];
    const float* sep8_w = (const float*)d_in[16]; const float* sep8_b = (const float*)d_in[17];
    const float* conv1_w = (const float*)d_in[18];
    const float* conv1_as = (const float*)d_in[19];
    const float* conv1_ad = (const float*)d_in[20];
    const float* conv1_b = (const float*)d_in[21];
    const float* conv2_w = (const float*)d_in[22];
    const float* conv2_as = (const float*)d_in[23];
    const float* conv2_ad = (const float*)d_in[24];
    const float* conv2_b = (const float*)d_in[25];
    const float* conv3_w = (const float*)d_in[26];
    const float* conv3_as = (const float*)d_in[27];
    const float* conv3_ad = (const float*)d_in[28];
    const float* conv3_b = (const float*)d_in[29];
    const float* lstm_wih = (const float*)d_in[30];
    const float* lstm_bih = (const float*)d_in[32];
    const float* lstm_bhh = (const float*)d_in[33];
    const float* lin1_w = (const float*)d_in[34]; const float* lin1_b = (const float*)d_in[35];
    const float* lin2_w = (const float*)d_in[36]; const float* lin2_b = (const float*)d_in[37];
    const float* lin3_w = (const float*)d_in[38]; const float* lin3_b = (const float*)d_in[39];

    char* ws = (char*)d_ws;
    size_t off = 0;
    auto alloc = [&](size_t bytes) {
        void* p = ws + off;
        off += (bytes + 255) & ~(size_t)255;
        return p;
    };
    short* x0 = (short*)alloc((size_t)NP * 384 * 2);  // reused for C / xg
    short* Bb = (short*)alloc((size_t)NP * 128 * 2);  // hw buffer
    float* ssrc = (float*)alloc((size_t)N * 4);
    float* sdst = (float*)alloc((size_t)N * 4);
    int* rowptr = (int*)alloc((size_t)(N + 1) * 4);
    int* nextp  = (int*)alloc((size_t)N * 4);
    int* cnt    = (int*)alloc((size_t)N * 4);
    int* bsum   = (int*)alloc((size_t)SCAN_BLOCKS * 4);
    int* colidx = (int*)alloc((size_t)E * 4);

    short* conv1p = (short*)alloc((size_t)128 * 384 * 2);
    short* conv2p = (short*)alloc((size_t)128 * 128 * 2);
    short* conv3p = (short*)alloc((size_t)64 * 128 * 2);
    short* sep1p  = (short*)alloc((size_t)64 * 32 * 2);
    short* sep2p  = (short*)alloc((size_t)64 * 32 * 2);
    short* sep3p  = (short*)alloc((size_t)128 * 64 * 2);
    short* sep4p  = (short*)alloc((size_t)128 * 384 * 2);
    short* sep5p  = (short*)alloc((size_t)64 * 64 * 2);
    short* sep6p  = (short*)alloc((size_t)64 * 64 * 2);
    short* sep7p  = (short*)alloc((size_t)128 * 128 * 2);
    short* sep8p  = (short*)alloc((size_t)128 * 128 * 2);
    short* lin1p  = (short*)alloc((size_t)64 * 128 * 2);
    short* lin2p  = (short*)alloc((size_t)64 * 64 * 2);
    short* lin3p  = (short*)alloc((size_t)64 * 64 * 2);

    size_t need_xs = off + (size_t)NP * 64 * 2 + (size_t)NP * 384 * 2 + 1024;
    bool packx = ws_size >= need_xs;
    short* xs3 = packx ? (short*)alloc((size_t)NP * 64 * 2) : nullptr;
    short* xs4 = packx ? (short*)alloc((size_t)NP * 384 * 2) : nullptr;

    short* C  = x0;       // GAT ping buffer (N,128)
    bf16* xg = (bf16*)x0; // GAT3 out (N,64)

    dim3 blk(256);
    int gx = NP / 64;  // 782
    int nb4 = (N + 3) / 4;
    int chunk = (N + SCAN_BLOCKS - 1) / SCAN_BLOCKS;

    // --- CSR build ---
    hipMemsetAsync(cnt, 0, (size_t)N * 4, stream);
    count_kernel<<<1024, 256, 0, stream>>>(e_dst, cnt, E);
    scan_local_kernel<<<SCAN_BLOCKS, 256, 0, stream>>>(cnt, rowptr, bsum, N, chunk);
    scan_bsums_kernel<<<1, 256, 0, stream>>>(bsum, rowptr, N);
    scan_add_kernel<<<SCAN_BLOCKS, 256, 0, stream>>>(rowptr, nextp, bsum, N, chunk);
    fill_kernel<<<1024, 256, 0, stream>>>(e_src, e_dst, nextp, colidx, E);

    // --- pack x slices (fast path) + weights (generic) to bf16 ---
    if (packx) {
        pack_x_kernel<48, 365, 56><<<(NP * 48 + 255) / 256, blk, 0, stream>>>(
            x_all, xs4, N);
        pack_x_kernel<8, 40, 16><<<(NP * 8 + 255) / 256, blk, 0, stream>>>(
            x_all, xs3, N);
    }
    {
        PackArgs pa{};
        unsigned long long total = 0;
        int np = 0;
        auto addp = [&](const float* src, short* dst, int lda, int M, int K,
                        int Mp, int Kp) {
            pa.d[np].src = src; pa.d[np].dst = dst; pa.d[np].lda = lda;
            pa.d[np].M = M; pa.d[np].K = K; pa.d[np].Mp = Mp; pa.d[np].Kp = Kp;
            pa.sz[np] = (unsigned long long)Mp * Kp;
            total += pa.sz[np];
            np++;
        };
        addp(conv1_w, conv1p, 384, 128, 384, 128, 384);
        addp(sep4_w, sep4p, 365, 128, 365, 128, 384);
        addp(conv2_w, conv2p, 128, 128, 128, 128, 128);
        addp(sep7_w, sep7p, 128, 128, 128, 128, 128);
        addp(sep8_w, sep8p, 128, 128, 128, 128, 128);
        addp(conv3_w, conv3p, 128, 64, 128, 64, 128);
        addp(lin1_w, lin1p, 128, 64, 128, 64, 128);
        addp(sep3_w, sep3p, 40, 128, 40, 128, 64);
        addp(sep5_w, sep5p, 64, 64, 64, 64, 64);
        addp(sep6_w, sep6p, 64, 64, 64, 64, 64);
        addp(lin2_w, lin2p, 64, 64, 64, 64, 64);
        addp(lin3_w, lin3p, 64, 56, 64, 64, 64);
        addp(sep1_w, sep1p, 2, 64, 2, 64, 32);
        addp(sep2_w, sep2p, 13, 64, 13, 64, 32);
        pa.n = np;
        pack_all_kernel<<<512, 256, 0, stream>>>(pa, total);
    }

    // --- four fused MLP branches -> x0 (N,384) bf16 ---
    brmlp_kernel<0, 4, 4, 1><<<gx, blk, 0, stream>>>(
        x_all, 441, 1, sep1p, sep1_b, sep5p, sep5_b, (bf16*)x0, 384, 0, N, 2);
    brmlp_kernel<0, 4, 4, 1><<<gx, blk, 0, stream>>>(
        x_all, 441, 3, sep2p, sep2_b, sep6p, sep6_b, (bf16*)x0, 384, 64, N, 13);
    if (packx) {
        brmlp_kernel<1, 8, 8, 2><<<gx, blk, 0, stream>>>(
            xs3, 64, 0, sep3p, sep3_b, sep7p, sep7_b, (bf16*)x0, 384, 128, N, 64);
        brmlp_kernel<1, 8, 8, 12><<<gx, blk, 0, stream>>>(
            xs4, 384, 0, sep4p, sep4_b, sep8p, sep8_b, (bf16*)x0, 384, 256, N, 384);
    } else {
        brmlp_kernel<0, 8, 8, 2><<<gx, blk, 0, stream>>>(
            x_all, 441, 16, sep3p, sep3_b, sep7p, sep7_b, (bf16*)x0, 384, 128, N, 40);
        brmlp_kernel<0, 8, 8, 12><<<gx, blk, 0, stream>>>(
            x_all, 441, 56, sep4p, sep4_b, sep8p, sep8_b, (bf16*)x0, 384, 256, N, 365);
    }

    // --- GAT layers (scores fused into GEMM epilogue; direct-load GEMM) ---
    dgemm_kernel<0, 1, 8, 12, 1><<<gx, blk, 0, stream>>>(
        x0, 384, conv1p, nullptr, Bb, 128, 0, N, 128,
        conv1_as, conv1_ad, ssrc, sdst);
    gat_fused_kernel<2><<<nb4, 256, 0, stream>>>(
        (const bf16*)Bb, rowptr, colidx, ssrc, sdst, conv1_b, (bf16*)C, 128, 0, N, 128);

    dgemm_kernel<0, 1, 8, 4, 1><<<gx, blk, 0, stream>>>(
        C, 128, conv2p, nullptr, Bb, 128, 0, N, 128,
        conv2_as, conv2_ad, ssrc, sdst);
    gat_fused_kernel<2><<<nb4, 256, 0, stream>>>(
        (const bf16*)Bb, rowptr, colidx, ssrc, sdst, conv2_b, (bf16*)C, 128, 0, N, 128);

    dgemm_kernel<0, 1, 4, 4, 1><<<gx, blk, 0, stream>>>(
        C, 128, conv3p, nullptr, Bb, 64, 0, N, 64,
        conv3_as, conv3_ad, ssrc, sdst);
    gat_fused_kernel<1><<<nb4, 256, 0, stream>>>(
        (const bf16*)Bb, rowptr, colidx, ssrc, sdst, conv3_b, xg, 64, 0, N, 64);

    // --- fused head: lstm + lin1 + lin2 + lin3 ---
    head_kernel<<<gx, blk, 0, stream>>>(
        xg, x_all, lstm_wih, lstm_bih, lstm_bhh,
        lin1p, lin1_b, lin2p, lin2_b, lin3p, lin3_b,
        (float*)d_out, N);
}